// Round 2
// baseline (410.961 us; speedup 1.0000x reference)
//
#include <hip/hip_runtime.h>

typedef __attribute__((ext_vector_type(8))) __bf16 bf16x8;
typedef __attribute__((ext_vector_type(8))) unsigned short ushort8v;
typedef __attribute__((ext_vector_type(4))) float f32x4;

__device__ __forceinline__ unsigned short f2bf(float f) {
  return __builtin_bit_cast(unsigned short, (__bf16)f);
}

// Swizzled byte offsets (XOR row-bits into the 16B-slot index -> no bank conflicts, G4)
__device__ __forceinline__ int qoff(int row, int colb) {  // 256B rows (A/Q/K[64][128] bf16)
  return row * 256 + (colb ^ ((row & 7) << 4));
}
__device__ __forceinline__ int toff(int row, int colb) {  // 128B rows (VT[128][64], S'[64][64] bf16)
  return row * 128 + (colb ^ ((row & 7) << 4));
}

// Barrier that does NOT drain vmcnt: LDS-ordering only. Keeps the next-row x prefetch
// and the out-stores in flight across phase barriers (T3/T4 discipline; __syncthreads
// would emit s_waitcnt vmcnt(0) and serialize HBM latency onto the critical path).
__device__ __forceinline__ void bar_lds() {
  asm volatile("s_waitcnt lgkmcnt(0)" ::: "memory");
  __builtin_amdgcn_s_barrier();
}

__global__ void prep_w(const float* __restrict__ Wq, const float* __restrict__ Wk,
                       const float* __restrict__ Wv, unsigned short* __restrict__ ws) {
  int i = blockIdx.x * 256 + threadIdx.x;
  if (i >= 3 * 16384) return;
  const float* s = (i < 16384) ? Wq : (i < 32768 ? Wk : Wv);
  ws[i] = f2bf(s[i & 16383]);
}

// 4 batch rows per block (grid 2048), software-pipelined: row r+1's x is prefetched
// into VGPRs during row r's GEMM chain; barriers are raw s_barrier + lgkmcnt(0) only,
// so global loads/stores stay in flight across all phase boundaries. Weights live in
// VGPRs for the whole block (amortized over 4 rows).
__global__ __launch_bounds__(512, 4) void fused_attn(
    const float* __restrict__ x, const unsigned short* __restrict__ wsW,
    const float* __restrict__ bq, const float* __restrict__ bk, const float* __restrict__ bv,
    const float* __restrict__ ln_w, const float* __restrict__ ln_b,
    float* __restrict__ out) {
  __shared__ __align__(16) unsigned char smem[66112];
  unsigned char* sA  = smem;            // xnorm A[64][128] bf16 (qoff); S'[64][64] (toff) overlays after B3
  unsigned char* sQ  = smem + 16384;    // Q[64][128] bf16 (qoff)
  unsigned char* sK  = smem + 32768;    // K[64][128] bf16 (qoff)
  unsigned char* sVT = smem + 49152;    // V^T[128][64] bf16 (toff)
  float* redS  = (float*)(smem + 65536);        // 16 floats LN scratch
  float* pPart = (float*)(smem + 65536 + 64);   // [8][16] S rowsum partials

  const int tid = threadIdx.x;
  const int lane = tid & 63;
  const int w = tid >> 6;            // wave 0..7
  const int l15 = lane & 15;
  const int l4 = lane >> 4;          // 0..3
  const size_t base = (size_t)blockIdx.x * (4 * 8192);

  // ---- weights -> VGPRs, once per block (amortized over 4 rows) ----
  bf16x8 wf[3][4];
  const int col = (w << 4) + l15;
#pragma unroll
  for (int m = 0; m < 3; ++m) {
    const unsigned short* wp = wsW + m * 16384 + col * 128 + (l4 << 3);
#pragma unroll
    for (int kk = 0; kk < 4; ++kk)
      wf[m][kk] = *(const bf16x8*)(wp + kk * 32);
  }
  const float biasQ = bq[col], biasK = bk[col], biasV = bv[col];

  const int row_x = tid >> 3;        // 0..63
  const int c0 = (tid & 7) << 4;     // 0..112

  // ---- prologue: load row 0's x slice ----
  float xv[16];
  {
    const float* xp = x + base + (size_t)row_x * 128 + c0;
#pragma unroll
    for (int i = 0; i < 4; ++i) {
      float4 a = *(const float4*)(xp + i * 4);
      xv[i*4+0]=a.x; xv[i*4+1]=a.y; xv[i*4+2]=a.z; xv[i*4+3]=a.w;
    }
  }

  for (int r = 0; r < 4; ++r) {
    const size_t bofs = base + (size_t)r * 8192;

    // ---- P0: LayerNorm reduce ----
    float s1 = 0.f, s2 = 0.f;
#pragma unroll
    for (int i = 0; i < 16; ++i) { s1 += xv[i]; s2 += xv[i] * xv[i]; }
#pragma unroll
    for (int off = 32; off > 0; off >>= 1) {
      s1 += __shfl_xor(s1, off, 64);
      s2 += __shfl_xor(s2, off, 64);
    }
    if (lane == 0) { redS[w] = s1; redS[8 + w] = s2; }
    bar_lds();  // B1

    // ln params (same slice every row, L2-hot after row 0); issue before stats math
    float lw[16], lb[16];
    {
      const float* pw = ln_w + row_x * 128 + c0;
      const float* pb = ln_b + row_x * 128 + c0;
#pragma unroll
      for (int i = 0; i < 4; ++i) {
        float4 a = *(const float4*)(pw + i * 4);
        lw[i*4+0]=a.x; lw[i*4+1]=a.y; lw[i*4+2]=a.z; lw[i*4+3]=a.w;
        float4 b = *(const float4*)(pb + i * 4);
        lb[i*4+0]=b.x; lb[i*4+1]=b.y; lb[i*4+2]=b.z; lb[i*4+3]=b.w;
      }
    }
    float t1 = 0.f, t2 = 0.f;
#pragma unroll
    for (int p = 0; p < 8; ++p) { t1 += redS[p]; t2 += redS[8 + p]; }
    const float mu = t1 * (1.f / 8192.f);
    const float rstd = rsqrtf(t2 * (1.f / 8192.f) - mu * mu + 1e-5f);

    // xnorm -> bf16 A in LDS (qoff layout)
#pragma unroll
    for (int h = 0; h < 2; ++h) {
      ushort8v t;
#pragma unroll
      for (int j = 0; j < 8; ++j)
        t[j] = f2bf((xv[h*8+j] - mu) * rstd * lw[h*8+j] + lb[h*8+j]);
      *(ushort8v*)(sA + qoff(row_x, (c0 << 1) + h * 16)) = t;
    }

    // prefetch next row's x NOW (pinned before B2 by the asm memory clobber);
    // stays in flight across GEMM1/S/V/P — ~4 phases of latency cover
    float xn[16];
    if (r < 3) {
      const float* xp = x + bofs + 8192 + (size_t)row_x * 128 + c0;
#pragma unroll
      for (int i = 0; i < 4; ++i) {
        float4 a = *(const float4*)(xp + i * 4);
        xn[i*4+0]=a.x; xn[i*4+1]=a.y; xn[i*4+2]=a.z; xn[i*4+3]=a.w;
      }
    }
    bar_lds();  // B2: A visible

    // ---- P1: GEMM1 (col-split): Q,K,V from reg-weights ----
#pragma unroll
    for (int mt = 0; mt < 4; ++mt) {
      bf16x8 aq[4];
#pragma unroll
      for (int kk = 0; kk < 4; ++kk)
        aq[kk] = *(const bf16x8*)(sA + qoff(mt * 16 + l15, kk * 64 + (l4 << 4)));
      const int i0m = mt * 16 + (l4 << 2);
      f32x4 aQ = {0,0,0,0}, aK = {0,0,0,0}, aV = {0,0,0,0};
#pragma unroll
      for (int kk = 0; kk < 4; ++kk) {
        aQ = __builtin_amdgcn_mfma_f32_16x16x32_bf16(aq[kk], wf[0][kk], aQ, 0, 0, 0);
        aK = __builtin_amdgcn_mfma_f32_16x16x32_bf16(aq[kk], wf[1][kk], aK, 0, 0, 0);
        aV = __builtin_amdgcn_mfma_f32_16x16x32_bf16(aq[kk], wf[2][kk], aV, 0, 0, 0);
      }
#pragma unroll
      for (int rr = 0; rr < 4; ++rr) {
        float zq = aQ[rr] + biasQ; zq = zq > 0.f ? zq + 1.f : __expf(zq);
        *(unsigned short*)(sQ + qoff(i0m + rr, col * 2)) = f2bf(zq);
        float zk = aK[rr] + biasK; zk = zk > 0.f ? zk + 1.f : __expf(zk);
        *(unsigned short*)(sK + qoff(i0m + rr, col * 2)) = f2bf(zk);
      }
      ushort4 pk;
      pk.x = f2bf(aV[0] + biasV); pk.y = f2bf(aV[1] + biasV);
      pk.z = f2bf(aV[2] + biasV); pk.w = f2bf(aV[3] + biasV);
      *(ushort4*)(sVT + toff(col, i0m * 2)) = pk;
    }
    bar_lds();  // B3: Q,K,VT visible; A dead

    // ---- P2: S = Q K^T; wave (st,half) -> rows [16st,16st+16) x cols [32half,32half+32) ----
    const int st = w >> 1;
    const int half = w & 1;
    const int i0s = st * 16 + (l4 << 2);
    f32x4 accS[2];
    {
      bf16x8 aq[4];
#pragma unroll
      for (int kk = 0; kk < 4; ++kk)
        aq[kk] = *(const bf16x8*)(sQ + qoff(st * 16 + l15, kk * 64 + (l4 << 4)));
#pragma unroll
      for (int nt = 0; nt < 2; ++nt) {
        const int ntg = half * 2 + nt;
        f32x4 acc = {0,0,0,0};
#pragma unroll
        for (int kk = 0; kk < 4; ++kk) {
          bf16x8 bk_ = *(const bf16x8*)(sK + qoff(ntg * 16 + l15, kk * 64 + (l4 << 4)));
          acc = __builtin_amdgcn_mfma_f32_16x16x32_bf16(aq[kk], bk_, acc, 0, 0, 0);
        }
        accS[nt] = acc;
      }
      float p[4];
#pragma unroll
      for (int rr = 0; rr < 4; ++rr) p[rr] = accS[0][rr] + accS[1][rr];
#pragma unroll
      for (int off = 1; off < 16; off <<= 1) {
#pragma unroll
        for (int rr = 0; rr < 4; ++rr) p[rr] += __shfl_xor(p[rr], off, 64);
      }
      if (l15 == 0) {
#pragma unroll
        for (int rr = 0; rr < 4; ++rr)
          pPart[w * 16 + (l4 << 2) + rr] = p[rr];
      }
    }
    bar_lds();  // B3b: partials visible

    // ---- P3: combine rowsum halves -> nv; S' (norm-folded) -> sA (toff) ----
    {
      float nv[4];
#pragma unroll
      for (int rr = 0; rr < 4; ++rr) {
        const int rI = (l4 << 2) + rr;
        nv[rr] = 1.f / (pPart[(st * 2) * 16 + rI] + pPart[(st * 2 + 1) * 16 + rI] + 1e-7f);
      }
#pragma unroll
      for (int nt = 0; nt < 2; ++nt) {
        const int ntg = half * 2 + nt;
#pragma unroll
        for (int rr = 0; rr < 4; ++rr)
          *(unsigned short*)(sA + toff(i0s + rr, (ntg * 16 + l15) * 2)) = f2bf(accS[nt][rr] * nv[rr]);
      }
    }
    bar_lds();  // B4: S' visible

    // ---- P4: P^T[m][l] = sum_i VT[m][i] S'[l][i]; residual add; store ----
    {
      bf16x8 av[2];
#pragma unroll
      for (int kk = 0; kk < 2; ++kk)
        av[kk] = *(const bf16x8*)(sVT + toff((w << 4) + l15, kk * 64 + (l4 << 4)));
#pragma unroll
      for (int nt = 0; nt < 4; ++nt) {
        bf16x8 bs0 = *(const bf16x8*)(sA + toff(nt * 16 + l15, (l4 << 4)));
        bf16x8 bs1 = *(const bf16x8*)(sA + toff(nt * 16 + l15, 64 + (l4 << 4)));
        f32x4 acc = {0,0,0,0};
        acc = __builtin_amdgcn_mfma_f32_16x16x32_bf16(av[0], bs0, acc, 0, 0, 0);
        acc = __builtin_amdgcn_mfma_f32_16x16x32_bf16(av[1], bs1, acc, 0, 0, 0);
        const int l = nt * 16 + l15;
        const int mb = (w << 4) + (l4 << 2);
        const size_t idx = bofs + (size_t)l * 128 + mb;
        float4 xr = *(const float4*)(x + idx);  // LLC-hot residual re-read
        float4 o;
        o.x = acc[0] + xr.x; o.y = acc[1] + xr.y;
        o.z = acc[2] + xr.z; o.w = acc[3] + xr.w;
        *(float4*)(out + idx) = o;
      }
    }

    // rotate pipeline regs (stores above stay in flight; xn already resident)
    if (r < 3) {
#pragma unroll
      for (int i = 0; i < 16; ++i) xv[i] = xn[i];
    }
  }
}

extern "C" void kernel_launch(void* const* d_in, const int* in_sizes, int n_in,
                              void* d_out, int out_size, void* d_ws, size_t ws_size,
                              hipStream_t stream) {
  const float* x   = (const float*)d_in[0];
  const float* Wq  = (const float*)d_in[1];
  const float* bq  = (const float*)d_in[2];
  const float* Wk  = (const float*)d_in[3];
  const float* bk  = (const float*)d_in[4];
  const float* Wv  = (const float*)d_in[5];
  const float* bv  = (const float*)d_in[6];
  const float* lnw = (const float*)d_in[7];
  const float* lnb = (const float*)d_in[8];
  unsigned short* ws = (unsigned short*)d_ws;  // 96 KB bf16 weights
  float* out = (float*)d_out;

  prep_w<<<192, 256, 0, stream>>>(Wq, Wk, Wv, ws);
  fused_attn<<<2048, 512, 0, stream>>>(x, ws, bq, bk, bv, lnw, lnb, out);
}

// Round 3
// 208.649 us; speedup vs baseline: 1.9696x; 1.9696x over previous
//
#include <hip/hip_runtime.h>

typedef __attribute__((ext_vector_type(8))) __bf16 bf16x8;
typedef __attribute__((ext_vector_type(8))) unsigned short ushort8v;
typedef __attribute__((ext_vector_type(4))) float f32x4;

__device__ __forceinline__ unsigned short f2bf(float f) {
  return __builtin_bit_cast(unsigned short, (__bf16)f);
}

// Swizzled byte offsets (XOR row-bits into the 16B-slot index -> no bank conflicts, G4)
__device__ __forceinline__ int qoff(int row, int colb) {  // 256B rows (A/Q/K[64][128] bf16)
  return row * 256 + (colb ^ ((row & 7) << 4));
}
__device__ __forceinline__ int toff(int row, int colb) {  // 128B rows (VT[128][64], S'[64][64] bf16)
  return row * 128 + (colb ^ ((row & 7) << 4));
}

// Barrier that does NOT drain vmcnt: LDS-ordering only (m201-verified pattern).
// Global loads/stores stay in flight across phase boundaries.
__device__ __forceinline__ void bar_lds() {
  asm volatile("s_waitcnt lgkmcnt(0)" ::: "memory");
  __builtin_amdgcn_s_barrier();
}

__global__ void prep_w(const float* __restrict__ Wq, const float* __restrict__ Wk,
                       const float* __restrict__ Wv, unsigned short* __restrict__ ws) {
  int i = blockIdx.x * 256 + threadIdx.x;
  if (i >= 3 * 16384) return;
  const float* s = (i < 16384) ? Wq : (i < 32768 ? Wk : Wv);
  ws[i] = f2bf(s[i & 16383]);
}

// 4 batch rows per block (grid 2048), software-pipelined, SPILL-FREE this time:
// launch_bounds(512,2) -> 128-VGPR cap (matches the 2-block/CU LDS residency; round 2's
// (512,4) imposed a CUDA-style 4-block = 64-VGPR cap and spilled ~360B/thread to scratch,
// inflating HBM traffic 2.5x). Live state cut: next row's x refills xv in place (no xn),
// ln_w/ln_b are re-issued per row (L2-hot) instead of register-cached.
__global__ __launch_bounds__(512, 2) void fused_attn(
    const float* __restrict__ x, const unsigned short* __restrict__ wsW,
    const float* __restrict__ bq, const float* __restrict__ bk, const float* __restrict__ bv,
    const float* __restrict__ ln_w, const float* __restrict__ ln_b,
    float* __restrict__ out) {
  __shared__ __align__(16) unsigned char smem[66112];
  unsigned char* sA  = smem;            // xnorm A[64][128] bf16 (qoff); S'[64][64] (toff) overlays after B3
  unsigned char* sQ  = smem + 16384;    // Q[64][128] bf16 (qoff)
  unsigned char* sK  = smem + 32768;    // K[64][128] bf16 (qoff)
  unsigned char* sVT = smem + 49152;    // V^T[128][64] bf16 (toff)
  float* redS  = (float*)(smem + 65536);        // 16 floats LN scratch
  float* pPart = (float*)(smem + 65536 + 64);   // [8][16] S rowsum partials

  const int tid = threadIdx.x;
  const int lane = tid & 63;
  const int w = tid >> 6;            // wave 0..7
  const int l15 = lane & 15;
  const int l4 = lane >> 4;          // 0..3
  const size_t base = (size_t)blockIdx.x * (4 * 8192);

  // ---- weights -> VGPRs, once per block (amortized over 4 rows) ----
  bf16x8 wf[3][4];
  const int col = (w << 4) + l15;
#pragma unroll
  for (int m = 0; m < 3; ++m) {
    const unsigned short* wp = wsW + m * 16384 + col * 128 + (l4 << 3);
#pragma unroll
    for (int kk = 0; kk < 4; ++kk)
      wf[m][kk] = *(const bf16x8*)(wp + kk * 32);
  }
  const float biasQ = bq[col], biasK = bk[col], biasV = bv[col];

  const int row_x = tid >> 3;        // 0..63
  const int c0 = (tid & 7) << 4;     // 0..112

  // ---- prologue: load row 0's x slice ----
  float xv[16];
  {
    const float* xp = x + base + (size_t)row_x * 128 + c0;
#pragma unroll
    for (int i = 0; i < 4; ++i) {
      float4 a = *(const float4*)(xp + i * 4);
      xv[i*4+0]=a.x; xv[i*4+1]=a.y; xv[i*4+2]=a.z; xv[i*4+3]=a.w;
    }
  }

#pragma unroll 1
  for (int r = 0; r < 4; ++r) {
    const size_t bofs = base + (size_t)r * 8192;

    // ln param loads issued FIRST (independent; L2-hot after gen 0) — latency hides
    // under the reduce + B1. Transient registers, dead after xnorm.
    float lw[16], lb[16];
    {
      const float* pw = ln_w + row_x * 128 + c0;
      const float* pb = ln_b + row_x * 128 + c0;
#pragma unroll
      for (int i = 0; i < 4; ++i) {
        float4 a = *(const float4*)(pw + i * 4);
        lw[i*4+0]=a.x; lw[i*4+1]=a.y; lw[i*4+2]=a.z; lw[i*4+3]=a.w;
        float4 b = *(const float4*)(pb + i * 4);
        lb[i*4+0]=b.x; lb[i*4+1]=b.y; lb[i*4+2]=b.z; lb[i*4+3]=b.w;
      }
    }

    // ---- P0: LayerNorm reduce (first use of xv -> waits only xv's loads) ----
    float s1 = 0.f, s2 = 0.f;
#pragma unroll
    for (int i = 0; i < 16; ++i) { s1 += xv[i]; s2 += xv[i] * xv[i]; }
#pragma unroll
    for (int off = 32; off > 0; off >>= 1) {
      s1 += __shfl_xor(s1, off, 64);
      s2 += __shfl_xor(s2, off, 64);
    }
    if (lane == 0) { redS[w] = s1; redS[8 + w] = s2; }
    bar_lds();  // B1

    float t1 = 0.f, t2 = 0.f;
#pragma unroll
    for (int p = 0; p < 8; ++p) { t1 += redS[p]; t2 += redS[8 + p]; }
    const float mu = t1 * (1.f / 8192.f);
    const float rstd = rsqrtf(t2 * (1.f / 8192.f) - mu * mu + 1e-5f);

    // xnorm -> bf16 A in LDS (consumes xv, lw, lb)
#pragma unroll
    for (int h = 0; h < 2; ++h) {
      ushort8v t;
#pragma unroll
      for (int j = 0; j < 8; ++j)
        t[j] = f2bf((xv[h*8+j] - mu) * rstd * lw[h*8+j] + lb[h*8+j]);
      *(ushort8v*)(sA + qoff(row_x, (c0 << 1) + h * 16)) = t;
    }

    // refill xv with next row's x NOW — in flight across GEMM1/S/P3/P4 (~whole row)
    if (r < 3) {
      const float* xp = x + bofs + 8192 + (size_t)row_x * 128 + c0;
#pragma unroll
      for (int i = 0; i < 4; ++i) {
        float4 a = *(const float4*)(xp + i * 4);
        xv[i*4+0]=a.x; xv[i*4+1]=a.y; xv[i*4+2]=a.z; xv[i*4+3]=a.w;
      }
    }
    bar_lds();  // B2: A visible

    // ---- P1: GEMM1 (col-split): Q,K,V from reg-weights ----
#pragma unroll
    for (int mt = 0; mt < 4; ++mt) {
      bf16x8 aq[4];
#pragma unroll
      for (int kk = 0; kk < 4; ++kk)
        aq[kk] = *(const bf16x8*)(sA + qoff(mt * 16 + l15, kk * 64 + (l4 << 4)));
      const int i0m = mt * 16 + (l4 << 2);
      f32x4 aQ = {0,0,0,0}, aK = {0,0,0,0}, aV = {0,0,0,0};
#pragma unroll
      for (int kk = 0; kk < 4; ++kk) {
        aQ = __builtin_amdgcn_mfma_f32_16x16x32_bf16(aq[kk], wf[0][kk], aQ, 0, 0, 0);
        aK = __builtin_amdgcn_mfma_f32_16x16x32_bf16(aq[kk], wf[1][kk], aK, 0, 0, 0);
        aV = __builtin_amdgcn_mfma_f32_16x16x32_bf16(aq[kk], wf[2][kk], aV, 0, 0, 0);
      }
#pragma unroll
      for (int rr = 0; rr < 4; ++rr) {
        float zq = aQ[rr] + biasQ; zq = zq > 0.f ? zq + 1.f : __expf(zq);
        *(unsigned short*)(sQ + qoff(i0m + rr, col * 2)) = f2bf(zq);
        float zk = aK[rr] + biasK; zk = zk > 0.f ? zk + 1.f : __expf(zk);
        *(unsigned short*)(sK + qoff(i0m + rr, col * 2)) = f2bf(zk);
      }
      ushort4 pk;
      pk.x = f2bf(aV[0] + biasV); pk.y = f2bf(aV[1] + biasV);
      pk.z = f2bf(aV[2] + biasV); pk.w = f2bf(aV[3] + biasV);
      *(ushort4*)(sVT + toff(col, i0m * 2)) = pk;
    }
    bar_lds();  // B3: Q,K,VT visible; A dead

    // ---- P2: S = Q K^T; wave (st,half) -> rows [16st,16st+16) x cols [32half,32half+32) ----
    const int st = w >> 1;
    const int half = w & 1;
    const int i0s = st * 16 + (l4 << 2);
    f32x4 accS[2];
    f32x4 xr[4];  // residual prefetch, used in P4
    {
      bf16x8 aq[4];
#pragma unroll
      for (int kk = 0; kk < 4; ++kk)
        aq[kk] = *(const bf16x8*)(sQ + qoff(st * 16 + l15, kk * 64 + (l4 << 4)));
#pragma unroll
      for (int nt = 0; nt < 2; ++nt) {
        const int ntg = half * 2 + nt;
        f32x4 acc = {0,0,0,0};
#pragma unroll
        for (int kk = 0; kk < 4; ++kk) {
          bf16x8 bk_ = *(const bf16x8*)(sK + qoff(ntg * 16 + l15, kk * 64 + (l4 << 4)));
          acc = __builtin_amdgcn_mfma_f32_16x16x32_bf16(aq[kk], bk_, acc, 0, 0, 0);
        }
        accS[nt] = acc;
      }
      float p[4];
#pragma unroll
      for (int rr = 0; rr < 4; ++rr) p[rr] = accS[0][rr] + accS[1][rr];
#pragma unroll
      for (int off = 1; off < 16; off <<= 1) {
#pragma unroll
        for (int rr = 0; rr < 4; ++rr) p[rr] += __shfl_xor(p[rr], off, 64);
      }
      if (l15 == 0) {
#pragma unroll
        for (int rr = 0; rr < 4; ++rr)
          pPart[w * 16 + (l4 << 2) + rr] = p[rr];
      }
      // residual x prefetch for P4 (LLC-hot; latency hidden under P3+B4)
#pragma unroll
      for (int nt = 0; nt < 4; ++nt) {
        const int l = nt * 16 + l15;
        const int mb = (w << 4) + (l4 << 2);
        xr[nt] = *(const f32x4*)(x + bofs + (size_t)l * 128 + mb);
      }
    }
    bar_lds();  // B3b: partials visible

    // ---- P3: combine rowsum halves -> nv; S' (norm-folded) -> sA (toff) ----
    {
      float nv[4];
#pragma unroll
      for (int rr = 0; rr < 4; ++rr) {
        const int rI = (l4 << 2) + rr;
        nv[rr] = 1.f / (pPart[(st * 2) * 16 + rI] + pPart[(st * 2 + 1) * 16 + rI] + 1e-7f);
      }
#pragma unroll
      for (int nt = 0; nt < 2; ++nt) {
        const int ntg = half * 2 + nt;
#pragma unroll
        for (int rr = 0; rr < 4; ++rr)
          *(unsigned short*)(sA + toff(i0s + rr, (ntg * 16 + l15) * 2)) = f2bf(accS[nt][rr] * nv[rr]);
      }
    }
    bar_lds();  // B4: S' visible

    // ---- P4: P^T[m][l] = sum_i VT[m][i] S'[l][i]; residual add; store ----
    {
      bf16x8 av[2];
#pragma unroll
      for (int kk = 0; kk < 2; ++kk)
        av[kk] = *(const bf16x8*)(sVT + toff((w << 4) + l15, kk * 64 + (l4 << 4)));
#pragma unroll
      for (int nt = 0; nt < 4; ++nt) {
        bf16x8 bs0 = *(const bf16x8*)(sA + toff(nt * 16 + l15, (l4 << 4)));
        bf16x8 bs1 = *(const bf16x8*)(sA + toff(nt * 16 + l15, 64 + (l4 << 4)));
        f32x4 acc = {0,0,0,0};
        acc = __builtin_amdgcn_mfma_f32_16x16x32_bf16(av[0], bs0, acc, 0, 0, 0);
        acc = __builtin_amdgcn_mfma_f32_16x16x32_bf16(av[1], bs1, acc, 0, 0, 0);
        const int l = nt * 16 + l15;
        const int mb = (w << 4) + (l4 << 2);
        const size_t idx = bofs + (size_t)l * 128 + mb;
        f32x4 o;
        o[0] = acc[0] + xr[nt][0]; o[1] = acc[1] + xr[nt][1];
        o[2] = acc[2] + xr[nt][2]; o[3] = acc[3] + xr[nt][3];
        *(f32x4*)(out + idx) = o;
      }
    }
    // no barrier here: next row's first LDS write (redS/sA) only happens after B1,
    // by which point every wave's P4 LDS reads are complete (lgkmcnt(0) at B1).
  }
}

extern "C" void kernel_launch(void* const* d_in, const int* in_sizes, int n_in,
                              void* d_out, int out_size, void* d_ws, size_t ws_size,
                              hipStream_t stream) {
  const float* x   = (const float*)d_in[0];
  const float* Wq  = (const float*)d_in[1];
  const float* bq  = (const float*)d_in[2];
  const float* Wk  = (const float*)d_in[3];
  const float* bk  = (const float*)d_in[4];
  const float* Wv  = (const float*)d_in[5];
  const float* bv  = (const float*)d_in[6];
  const float* lnw = (const float*)d_in[7];
  const float* lnb = (const float*)d_in[8];
  unsigned short* ws = (unsigned short*)d_ws;  // 96 KB bf16 weights
  float* out = (float*)d_out;

  prep_w<<<192, 256, 0, stream>>>(Wq, Wk, Wv, ws);
  fused_attn<<<2048, 512, 0, stream>>>(x, ws, bq, bk, bv, lnw, lnb, out);
}